// Round 12
// baseline (64.730 us; speedup 1.0000x reference)
//
#include <hip/hip_runtime.h>
#include <hip/hip_fp16.h>
#include <math.h>

#define MAGB 0.01f

__device__ __forceinline__ int refl(int i, int n) {
  if (i < 0) i = -1 - i;
  if (i >= n) i = 2 * n - 1 - i;
  return i;
}

__device__ __forceinline__ float magf(float re, float im) {
  return sqrtf(re * re + im * im + MAGB * MAGB) - MAGB;
}

// 16-wide window v[0..15] (cols cb-4..cb+11) -> 8 outputs (cols cb..cb+7)
__device__ __forceinline__ void filt8_win(const float* __restrict__ v,
                                          const float* __restrict__ f0,
                                          const float* __restrict__ f1,
                                          float* o0, float* o1) {
#pragma unroll
  for (int k = 0; k < 8; ++k) {
    float a0 = 0.f, a1 = 0.f;
#pragma unroll
    for (int j = 0; j < 5; ++j) a0 += f0[j] * v[k + 2 + j];
#pragma unroll
    for (int j = 0; j < 7; ++j) a1 += f1[j] * v[k + 1 + j];
    o0[k] = a0; o1[k] = a1;
  }
}

#define J1_STRIDE 36

// j1 column filter: 8-row window over 4 LDS columns -> ll/lh/hl/hh [dr][4]
struct J1Acc {
  float ll[2][4], lh[2][4], hl[2][4], hh[2][4];
};

__device__ __forceinline__ void j1_colfilt4(
    const float* __restrict__ lo_s, const float* __restrict__ hi_s,
    int row0, int col, const float* __restrict__ f0, const float* __restrict__ f1,
    J1Acc* A) {
#pragma unroll
  for (int dr = 0; dr < 2; ++dr)
#pragma unroll
    for (int c = 0; c < 4; ++c) {
      A->ll[dr][c] = 0.f; A->lh[dr][c] = 0.f; A->hl[dr][c] = 0.f; A->hh[dr][c] = 0.f;
    }
#pragma unroll
  for (int tt = 0; tt < 8; ++tt) {
    float4 lv4 = *(const float4*)(lo_s + (row0 + tt) * J1_STRIDE + col);
    float4 hv4 = *(const float4*)(hi_s + (row0 + tt) * J1_STRIDE + col);
    float lv[4] = {lv4.x, lv4.y, lv4.z, lv4.w};
    float hv[4] = {hv4.x, hv4.y, hv4.z, hv4.w};
#pragma unroll
    for (int dr = 0; dr < 2; ++dr) {
      int j0 = tt - dr - 1;  // 5-tap index
      int j1 = tt - dr;      // 7-tap index
#pragma unroll
      for (int c = 0; c < 4; ++c) {
        if (j0 >= 0 && j0 < 5) {
          A->ll[dr][c] += f0[j0] * lv[c];
          A->hl[dr][c] += f0[j0] * hv[c];
        }
        if (j1 >= 0 && j1 < 7) {
          A->lh[dr][c] += f1[j1] * lv[c];
          A->hh[dr][c] += f1[j1] * hv[c];
        }
      }
    }
  }
}

__device__ __forceinline__ void q2c_mag_k(const float v[2][4], int k,
                                          float* mlo, float* mhi) {
  float a = v[0][2 * k], b = v[0][2 * k + 1], c = v[1][2 * k], d = v[1][2 * k + 1];
  *mlo = magf((a + d) * 0.5f, (b - c) * 0.5f);
  *mhi = magf((a - d) * 0.5f, (b + c) * 0.5f);
}

// ---------------------------------------------------------------------------
// Stage A: fused j1 on x (8,3,512,512). Tile half-res 32x16 (full 64x32).
// Phase 1: 70 rows x 4 groups of 8 cols (280 units). LDS stride 36, 20.2 KB.
// Writes s0 (f32) + pb (fp16, (N,18,256,256)).
// ---------------------------------------------------------------------------
__global__ __launch_bounds__(256) void k_fused_j1a(
    const float* __restrict__ x,
    const float* __restrict__ h0, const float* __restrict__ h1,
    float* __restrict__ s0, __half* __restrict__ pb) {
  constexpr int H = 512, W = 512;
  __shared__ float lo_s[70 * J1_STRIDE];
  __shared__ float hi_s[70 * J1_STRIDE];
  int p = blockIdx.x >> 7;             // 128 tiles/plane
  int tloc = blockIdx.x & 127;
  int th = tloc >> 4, tw = tloc & 15;  // 8 x 16 tiles
  int h2_0 = th << 5, w2_0 = tw << 4;
  int c0 = w2_0 << 1;                  // full-res col base (32-wide)
  const float* xp = x + (size_t)p * (H * W);
  float f0[5], f1[7];
#pragma unroll
  for (int j = 0; j < 5; ++j) f0[j] = h0[j];
#pragma unroll
  for (int j = 0; j < 7; ++j) f1[j] = h1[j];
  int tid = threadIdx.x;

  // Phase 1: row filter -> LDS (70 rows x 4 groups of 8 cols)
  for (int e = tid; e < 70 * 4; e += 256) {
    int r = e >> 2, g = e & 3;
    int row = refl((h2_0 << 1) - 3 + r, H);
    const float* xr = xp + (size_t)row * W;
    int cb = c0 + (g << 3);
    float v[16];
    if (cb >= 4 && cb + 12 <= W) {
      float4 q0 = *(const float4*)(xr + cb - 4);
      float4 q1 = *(const float4*)(xr + cb);
      float4 q2 = *(const float4*)(xr + cb + 4);
      float4 q3 = *(const float4*)(xr + cb + 8);
      v[0] = q0.x; v[1] = q0.y; v[2] = q0.z; v[3] = q0.w;
      v[4] = q1.x; v[5] = q1.y; v[6] = q1.z; v[7] = q1.w;
      v[8] = q2.x; v[9] = q2.y; v[10] = q2.z; v[11] = q2.w;
      v[12] = q3.x; v[13] = q3.y; v[14] = q3.z; v[15] = q3.w;
    } else {
      v[0] = 0.f; v[15] = 0.f;
#pragma unroll
      for (int t = 1; t <= 14; ++t) v[t] = xr[refl(cb - 4 + t, W)];
    }
    float o0[8], o1[8];
    filt8_win(v, f0, f1, o0, o1);
    *(float4*)&lo_s[r * J1_STRIDE + (g << 3)] = make_float4(o0[0], o0[1], o0[2], o0[3]);
    *(float4*)&lo_s[r * J1_STRIDE + (g << 3) + 4] = make_float4(o0[4], o0[5], o0[6], o0[7]);
    *(float4*)&hi_s[r * J1_STRIDE + (g << 3)] = make_float4(o1[0], o1[1], o1[2], o1[3]);
    *(float4*)&hi_s[r * J1_STRIDE + (g << 3) + 4] = make_float4(o1[4], o1[5], o1[6], o1[7]);
  }
  __syncthreads();

  // Phase 2: one output-pair per thread (32 hq x 8 w-pairs)
  int n = p / 3, ch = p - 3 * n;
  float* s0p = s0 + (size_t)p * (H * W);
  constexpr int sp2 = 256 * 256;
  __half* pbb = pb + (size_t)n * 18 * sp2;
  int hq = tid >> 3, wq = tid & 7;
  int h2 = h2_0 + hq;
  int w2 = w2_0 + (wq << 1);
  J1Acc A;
  j1_colfilt4(lo_s, hi_s, hq << 1, wq << 2, f0, f1, &A);
#pragma unroll
  for (int dr = 0; dr < 2; ++dr) {
    *(float4*)&s0p[(size_t)((h2 << 1) + dr) * W + c0 + (wq << 2)] =
        make_float4(A.ll[dr][0], A.ll[dr][1], A.ll[dr][2], A.ll[dr][3]);
  }
  float m2[6][2];
#pragma unroll
  for (int k = 0; k < 2; ++k) {
    q2c_mag_k(A.lh, k, &m2[0][k], &m2[5][k]);
    q2c_mag_k(A.hh, k, &m2[1][k], &m2[4][k]);
    q2c_mag_k(A.hl, k, &m2[2][k], &m2[3][k]);
  }
#pragma unroll
  for (int o6 = 0; o6 < 6; ++o6) {
    *(__half2*)&pbb[(size_t)(o6 * 3 + ch) * sp2 + (h2 << 8) + w2] =
        __floats2half2_rn(m2[o6][0], m2[o6][1]);
  }
}

// ---------------------------------------------------------------------------
// Merged stage B (blocks 0..1535) + stage C (blocks 1536..6143).
// B: fused j2 on s0 (f32 24x512x512), tile quarter-res 16x16, stride 36.
// C: fused j1 on pb (fp16 144x256x256), tile half-res 32x16, stride 36.
// ---------------------------------------------------------------------------
#define B_STRIDE 36

__global__ __launch_bounds__(256) void k_fused_bc(
    const float* __restrict__ s0, const __half* __restrict__ pb,
    const float* __restrict__ h0a, const float* __restrict__ h0b,
    const float* __restrict__ h1a, const float* __restrict__ h1b,
    const float* __restrict__ h0, const float* __restrict__ h1,
    float* __restrict__ out) {
  __shared__ float smem[5760];  // B: 2x 80*36=5760; C: 2x 70*36=5040
  int tid = threadIdx.x;
  constexpr int spo = 128 * 128;

  if (blockIdx.x < 1536) {
    // ---------------- Stage B ----------------
    constexpr int H = 512, W = 512;
    float* lo2_s = smem;          // [80][36]
    float* hi2_s = smem + 2880;
    int p = blockIdx.x >> 6;
    int tloc = blockIdx.x & 63;
    int th = tloc >> 3, tw = tloc & 7;
    int h4_0 = th << 4, w4_0 = tw << 4;
    const float* sp = s0 + (size_t)p * (H * W);
    float fa0[10], fb0[10], fa1[10], fb1[10];
#pragma unroll
    for (int j = 0; j < 10; ++j) {
      fa0[j] = h0a[j]; fb0[j] = h0b[j]; fa1[j] = h1a[j]; fb1[j] = h1b[j];
    }

    // Phase 1: row dfilt -> LDS; column-pair (4 outputs) from 6 float4s
    for (int e = tid; e < 80 * 8; e += 256) {
      int hr = e >> 3, g = e & 7;
      int row = refl((h4_0 << 2) - 8 + hr, H);
      const float* xr = sp + (size_t)row * W;
      int i0 = w4_0 + (g << 1);
      int base = (i0 << 2) - 8;
      float v[24];
      if (base >= 0 && base + 24 <= W) {
        const float* xb = xr + base;
#pragma unroll
        for (int q = 0; q < 6; ++q) {
          float4 t = *(const float4*)(xb + (q << 2));
          v[4 * q] = t.x; v[4 * q + 1] = t.y; v[4 * q + 2] = t.z; v[4 * q + 3] = t.w;
        }
      } else {
#pragma unroll
        for (int t = 0; t < 24; ++t) v[t] = xr[refl(base + t, W)];
      }
      float r0[4], r1[4];
#pragma unroll
      for (int k = 0; k < 2; ++k) {
        float ya0 = 0.f, yb0 = 0.f, ya1 = 0.f, yb1 = 0.f;
#pragma unroll
        for (int j = 0; j < 10; ++j) {
          float ve = v[4 * k + 2 * j], vo = v[4 * k + 2 * j + 1];
          ya0 += fa0[j] * ve; yb0 += fb0[j] * vo;
          ya1 += fa1[j] * ve; yb1 += fb1[j] * vo;
        }
        r0[2 * k] = ya0; r0[2 * k + 1] = yb0;
        r1[2 * k] = yb1; r1[2 * k + 1] = ya1;  // highpass: first=yb
      }
      *(float4*)&lo2_s[hr * B_STRIDE + (g << 2)] = make_float4(r0[0], r0[1], r0[2], r0[3]);
      *(float4*)&hi2_s[hr * B_STRIDE + (g << 2)] = make_float4(r1[0], r1[1], r1[2], r1[3]);
    }
    __syncthreads();

    // Phase 2: col dfilt + q2c + mag + pooled ll (1 output/thread)
    int h4l = tid >> 4, w4l = tid & 15;
    int h4 = h4_0 + h4l, w4 = w4_0 + w4l;
    int cl = w4l << 1;
    float a0l[2] = {0.f, 0.f}, b0l[2] = {0.f, 0.f}, a1l[2] = {0.f, 0.f}, b1l[2] = {0.f, 0.f};
    float a0h[2] = {0.f, 0.f}, b0h[2] = {0.f, 0.f}, a1h[2] = {0.f, 0.f}, b1h[2] = {0.f, 0.f};
#pragma unroll
    for (int j = 0; j < 10; ++j) {
      int hre = (h4l << 2) + 2 * j;
      float2 le = *(const float2*)&lo2_s[hre * B_STRIDE + cl];
      float2 lo_ = *(const float2*)&lo2_s[(hre + 1) * B_STRIDE + cl];
      float2 he = *(const float2*)&hi2_s[hre * B_STRIDE + cl];
      float2 ho = *(const float2*)&hi2_s[(hre + 1) * B_STRIDE + cl];
      a0l[0] += fa0[j] * le.x;  a0l[1] += fa0[j] * le.y;
      b0l[0] += fb0[j] * lo_.x; b0l[1] += fb0[j] * lo_.y;
      a1l[0] += fa1[j] * le.x;  a1l[1] += fa1[j] * le.y;
      b1l[0] += fb1[j] * lo_.x; b1l[1] += fb1[j] * lo_.y;
      a0h[0] += fa0[j] * he.x;  a0h[1] += fa0[j] * he.y;
      b0h[0] += fb0[j] * ho.x;  b0h[1] += fb0[j] * ho.y;
      a1h[0] += fa1[j] * he.x;  a1h[1] += fa1[j] * he.y;
      b1h[0] += fb1[j] * ho.x;  b1h[1] += fb1[j] * ho.y;
    }
    float llv[2][2], lhv[2][2], hlv[2][2], hhv[2][2];
#pragma unroll
    for (int dc = 0; dc < 2; ++dc) {
      llv[0][dc] = a0l[dc]; llv[1][dc] = b0l[dc];
      lhv[0][dc] = b1l[dc]; lhv[1][dc] = a1l[dc];
      hlv[0][dc] = a0h[dc]; hlv[1][dc] = b0h[dc];
      hhv[0][dc] = b1h[dc]; hhv[1][dc] = a1h[dc];
    }
    int n = p / 3, ch = p - 3 * n;
    float* ob = out + (size_t)n * 147 * spo + ((size_t)h4 << 7) + w4;
    ob[(size_t)ch * spo] = 0.25f * (llv[0][0] + llv[0][1] + llv[1][0] + llv[1][1]);
    float m[6];
    { float a = lhv[0][0], b = lhv[0][1], c = lhv[1][0], d = lhv[1][1];
      m[0] = magf((a + d) * 0.5f, (b - c) * 0.5f);
      m[5] = magf((a - d) * 0.5f, (b + c) * 0.5f); }
    { float a = hhv[0][0], b = hhv[0][1], c = hhv[1][0], d = hhv[1][1];
      m[1] = magf((a + d) * 0.5f, (b - c) * 0.5f);
      m[4] = magf((a - d) * 0.5f, (b + c) * 0.5f); }
    { float a = hlv[0][0], b = hlv[0][1], c = hlv[1][0], d = hlv[1][1];
      m[2] = magf((a + d) * 0.5f, (b - c) * 0.5f);
      m[3] = magf((a - d) * 0.5f, (b + c) * 0.5f); }
#pragma unroll
    for (int o = 0; o < 6; ++o) {
      ob[(size_t)((7 + o) * 3 + ch) * spo] = m[o];
    }
  } else {
    // ---------------- Stage C (pb fp16, 144x256x256), tile 32x16 ----------
    constexpr int H = 256, W = 256;
    float* lo_s = smem;           // [70][36]
    float* hi_s = smem + 2520;
    int bid = blockIdx.x - 1536;
    int p = bid >> 5;             // 32 tiles/plane
    int tloc = bid & 31;
    int th = tloc >> 3, tw = tloc & 7;  // 4 x 8 tiles
    int h2_0 = th << 5, w2_0 = tw << 4;
    int c0 = w2_0 << 1;           // 0..224
    const __half* xp = pb + (size_t)p * (H * W);
    float f0[5], f1[7];
#pragma unroll
    for (int j = 0; j < 5; ++j) f0[j] = h0[j];
#pragma unroll
    for (int j = 0; j < 7; ++j) f1[j] = h1[j];

    // Phase 1: fp16 row filter -> LDS (70 rows x 4 groups of 8 cols)
    for (int e = tid; e < 70 * 4; e += 256) {
      int r = e >> 2, g = e & 3;
      int row = refl((h2_0 << 1) - 3 + r, H);
      const __half* xr = xp + (size_t)row * W;
      int cb = c0 + (g << 3);
      float v[16];
      if (cb >= 4 && cb + 12 <= W) {
        union { uint2 u; __half2 h[2]; } q0, q1, q2, q3;
        q0.u = *(const uint2*)(xr + cb - 4);
        q1.u = *(const uint2*)(xr + cb);
        q2.u = *(const uint2*)(xr + cb + 4);
        q3.u = *(const uint2*)(xr + cb + 8);
        float2 t;
        t = __half22float2(q0.h[0]); v[0] = t.x; v[1] = t.y;
        t = __half22float2(q0.h[1]); v[2] = t.x; v[3] = t.y;
        t = __half22float2(q1.h[0]); v[4] = t.x; v[5] = t.y;
        t = __half22float2(q1.h[1]); v[6] = t.x; v[7] = t.y;
        t = __half22float2(q2.h[0]); v[8] = t.x; v[9] = t.y;
        t = __half22float2(q2.h[1]); v[10] = t.x; v[11] = t.y;
        t = __half22float2(q3.h[0]); v[12] = t.x; v[13] = t.y;
        t = __half22float2(q3.h[1]); v[14] = t.x; v[15] = t.y;
      } else {
        v[0] = 0.f; v[15] = 0.f;
#pragma unroll
        for (int t2 = 1; t2 <= 14; ++t2) v[t2] = __half2float(xr[refl(cb - 4 + t2, W)]);
      }
      float o0[8], o1[8];
      filt8_win(v, f0, f1, o0, o1);
      *(float4*)&lo_s[r * J1_STRIDE + (g << 3)] = make_float4(o0[0], o0[1], o0[2], o0[3]);
      *(float4*)&lo_s[r * J1_STRIDE + (g << 3) + 4] = make_float4(o0[4], o0[5], o0[6], o0[7]);
      *(float4*)&hi_s[r * J1_STRIDE + (g << 3)] = make_float4(o1[0], o1[1], o1[2], o1[3]);
      *(float4*)&hi_s[r * J1_STRIDE + (g << 3) + 4] = make_float4(o1[4], o1[5], o1[6], o1[7]);
    }
    __syncthreads();

    int c18 = p % 18, n = p / 18;
    int o1i = c18 / 3, ch = c18 - 3 * o1i;
    float* ob = out + (size_t)n * 147 * spo;
    int hq = tid >> 3, wq = tid & 7;
    int h2 = h2_0 + hq;
    int w2 = w2_0 + (wq << 1);
    J1Acc A;
    j1_colfilt4(lo_s, hi_s, hq << 1, wq << 2, f0, f1, &A);
    size_t px = ((size_t)h2 << 7) + w2;
    float pl0 = 0.25f * (A.ll[0][0] + A.ll[0][1] + A.ll[1][0] + A.ll[1][1]);
    float pl1 = 0.25f * (A.ll[0][2] + A.ll[0][3] + A.ll[1][2] + A.ll[1][3]);
    *(float2*)&ob[(size_t)((1 + o1i) * 3 + ch) * spo + px] = make_float2(pl0, pl1);
    float m2[6][2];
#pragma unroll
    for (int k = 0; k < 2; ++k) {
      q2c_mag_k(A.lh, k, &m2[0][k], &m2[5][k]);
      q2c_mag_k(A.hh, k, &m2[1][k], &m2[4][k]);
      q2c_mag_k(A.hl, k, &m2[2][k], &m2[3][k]);
    }
#pragma unroll
    for (int o2 = 0; o2 < 6; ++o2) {
      *(float2*)&ob[(size_t)((13 + o2 * 6 + o1i) * 3 + ch) * spo + px] =
          make_float2(m2[o2][0], m2[o2][1]);
    }
  }
}

extern "C" void kernel_launch(void* const* d_in, const int* in_sizes, int n_in,
                              void* d_out, int out_size, void* d_ws, size_t ws_size,
                              hipStream_t stream) {
  const float* x   = (const float*)d_in[0];
  const float* h0o = (const float*)d_in[1];
  const float* h1o = (const float*)d_in[2];
  const float* h0a = (const float*)d_in[3];
  const float* h0b = (const float*)d_in[4];
  const float* h1a = (const float*)d_in[5];
  const float* h1b = (const float*)d_in[6];
  float* out = (float*)d_out;
  char* ws = (char*)d_ws;
  (void)in_sizes; (void)n_in; (void)out_size; (void)ws_size;

  // Workspace: s0 f32 (24x512x512 = 24 MB), pb fp16 (8x18x256x256 = 18.9 MB)
  const size_t SZ_S0 = (size_t)24 * 512 * 512 * sizeof(float);
  float* s0 = (float*)ws;
  __half* pb = (__half*)(ws + SZ_S0);

  k_fused_j1a<<<3072, 256, 0, stream>>>(x, h0o, h1o, s0, pb);
  k_fused_bc<<<6144, 256, 0, stream>>>(s0, pb, h0a, h0b, h1a, h1b, h0o, h1o, out);
}

// Round 13
// 60.180 us; speedup vs baseline: 1.0756x; 1.0756x over previous
//
#include <hip/hip_runtime.h>
#include <hip/hip_fp16.h>
#include <math.h>

#define MAGB 0.01f

__device__ __forceinline__ int refl(int i, int n) {
  if (i < 0) i = -1 - i;
  if (i >= n) i = 2 * n - 1 - i;
  return i;
}

__device__ __forceinline__ float magf(float re, float im) {
  return sqrtf(re * re + im * im + MAGB * MAGB) - MAGB;
}

// 16-wide window v[0..15] (cols cb-4..cb+11) -> 8 outputs (cols cb..cb+7)
__device__ __forceinline__ void filt8_win(const float* __restrict__ v,
                                          const float* __restrict__ f0,
                                          const float* __restrict__ f1,
                                          float* o0, float* o1) {
#pragma unroll
  for (int k = 0; k < 8; ++k) {
    float a0 = 0.f, a1 = 0.f;
#pragma unroll
    for (int j = 0; j < 5; ++j) a0 += f0[j] * v[k + 2 + j];
#pragma unroll
    for (int j = 0; j < 7; ++j) a1 += f1[j] * v[k + 1 + j];
    o0[k] = a0; o1[k] = a1;
  }
}

#define J1_STRIDE 68

// j1 column filter: 8-row window over 4 LDS columns -> ll/lh/hl/hh [dr][4]
struct J1Acc {
  float ll[2][4], lh[2][4], hl[2][4], hh[2][4];
};

__device__ __forceinline__ void j1_colfilt4(
    const float* __restrict__ lo_s, const float* __restrict__ hi_s,
    int row0, int col, const float* __restrict__ f0, const float* __restrict__ f1,
    J1Acc* A) {
#pragma unroll
  for (int dr = 0; dr < 2; ++dr)
#pragma unroll
    for (int c = 0; c < 4; ++c) {
      A->ll[dr][c] = 0.f; A->lh[dr][c] = 0.f; A->hl[dr][c] = 0.f; A->hh[dr][c] = 0.f;
    }
#pragma unroll
  for (int tt = 0; tt < 8; ++tt) {
    float4 lv4 = *(const float4*)(lo_s + (row0 + tt) * J1_STRIDE + col);
    float4 hv4 = *(const float4*)(hi_s + (row0 + tt) * J1_STRIDE + col);
    float lv[4] = {lv4.x, lv4.y, lv4.z, lv4.w};
    float hv[4] = {hv4.x, hv4.y, hv4.z, hv4.w};
#pragma unroll
    for (int dr = 0; dr < 2; ++dr) {
      int j0 = tt - dr - 1;  // 5-tap index
      int j1 = tt - dr;      // 7-tap index
#pragma unroll
      for (int c = 0; c < 4; ++c) {
        if (j0 >= 0 && j0 < 5) {
          A->ll[dr][c] += f0[j0] * lv[c];
          A->hl[dr][c] += f0[j0] * hv[c];
        }
        if (j1 >= 0 && j1 < 7) {
          A->lh[dr][c] += f1[j1] * lv[c];
          A->hh[dr][c] += f1[j1] * hv[c];
        }
      }
    }
  }
}

__device__ __forceinline__ void q2c_mag_k(const float v[2][4], int k,
                                          float* mlo, float* mhi) {
  float a = v[0][2 * k], b = v[0][2 * k + 1], c = v[1][2 * k], d = v[1][2 * k + 1];
  *mlo = magf((a + d) * 0.5f, (b - c) * 0.5f);
  *mhi = magf((a - d) * 0.5f, (b + c) * 0.5f);
}

// ---------------------------------------------------------------------------
// Stage A: fused j1 on x (8,3,512,512). Tile half-res 16x32 (full 32x64).
// Phase 1: 8-wide units (38 rows x 8 groups). Writes s0 (f32) + pb (fp16).
// ---------------------------------------------------------------------------
__global__ __launch_bounds__(256) void k_fused_j1a(
    const float* __restrict__ x,
    const float* __restrict__ h0, const float* __restrict__ h1,
    float* __restrict__ s0, __half* __restrict__ pb) {
  constexpr int H = 512, W = 512;
  __shared__ float lo_s[38 * J1_STRIDE];
  __shared__ float hi_s[38 * J1_STRIDE];
  int p = blockIdx.x >> 7;            // 128 tiles/plane
  int tloc = blockIdx.x & 127;
  int th = tloc >> 3, tw = tloc & 7;  // 16 x 8 tiles
  int h2_0 = th << 4, w2_0 = tw << 5;
  int c0 = w2_0 << 1;
  const float* xp = x + (size_t)p * (H * W);
  float f0[5], f1[7];
#pragma unroll
  for (int j = 0; j < 5; ++j) f0[j] = h0[j];
#pragma unroll
  for (int j = 0; j < 7; ++j) f1[j] = h1[j];
  int tid = threadIdx.x;

  // Phase 1: row filter -> LDS (38 rows x 8 groups of 8 cols)
  for (int e = tid; e < 38 * 8; e += 256) {
    int r = e >> 3, g = e & 7;
    int row = refl((h2_0 << 1) - 3 + r, H);
    const float* xr = xp + (size_t)row * W;
    int cb = c0 + (g << 3);
    float v[16];
    if (cb >= 4 && cb + 12 <= W) {
      float4 q0 = *(const float4*)(xr + cb - 4);
      float4 q1 = *(const float4*)(xr + cb);
      float4 q2 = *(const float4*)(xr + cb + 4);
      float4 q3 = *(const float4*)(xr + cb + 8);
      v[0] = q0.x; v[1] = q0.y; v[2] = q0.z; v[3] = q0.w;
      v[4] = q1.x; v[5] = q1.y; v[6] = q1.z; v[7] = q1.w;
      v[8] = q2.x; v[9] = q2.y; v[10] = q2.z; v[11] = q2.w;
      v[12] = q3.x; v[13] = q3.y; v[14] = q3.z; v[15] = q3.w;
    } else {
      v[0] = 0.f; v[15] = 0.f;
#pragma unroll
      for (int t = 1; t <= 14; ++t) v[t] = xr[refl(cb - 4 + t, W)];
    }
    float o0[8], o1[8];
    filt8_win(v, f0, f1, o0, o1);
    *(float4*)&lo_s[r * J1_STRIDE + (g << 3)] = make_float4(o0[0], o0[1], o0[2], o0[3]);
    *(float4*)&lo_s[r * J1_STRIDE + (g << 3) + 4] = make_float4(o0[4], o0[5], o0[6], o0[7]);
    *(float4*)&hi_s[r * J1_STRIDE + (g << 3)] = make_float4(o1[0], o1[1], o1[2], o1[3]);
    *(float4*)&hi_s[r * J1_STRIDE + (g << 3) + 4] = make_float4(o1[4], o1[5], o1[6], o1[7]);
  }
  __syncthreads();

  // Phase 2: one output-pair per thread (16 hq x 16 w-pairs)
  int n = p / 3, ch = p - 3 * n;
  float* s0p = s0 + (size_t)p * (H * W);
  constexpr int sp2 = 256 * 256;
  __half* pbb = pb + (size_t)n * 18 * sp2;
  int hq = tid >> 4, wq = tid & 15;
  int h2 = h2_0 + hq;
  int w2 = w2_0 + (wq << 1);
  J1Acc A;
  j1_colfilt4(lo_s, hi_s, hq << 1, wq << 2, f0, f1, &A);
#pragma unroll
  for (int dr = 0; dr < 2; ++dr) {
    *(float4*)&s0p[(size_t)((h2 << 1) + dr) * W + (w2 << 1)] =
        make_float4(A.ll[dr][0], A.ll[dr][1], A.ll[dr][2], A.ll[dr][3]);
  }
  float m2[6][2];
#pragma unroll
  for (int k = 0; k < 2; ++k) {
    q2c_mag_k(A.lh, k, &m2[0][k], &m2[5][k]);
    q2c_mag_k(A.hh, k, &m2[1][k], &m2[4][k]);
    q2c_mag_k(A.hl, k, &m2[2][k], &m2[3][k]);
  }
#pragma unroll
  for (int o6 = 0; o6 < 6; ++o6) {
    *(__half2*)&pbb[(size_t)(o6 * 3 + ch) * sp2 + (h2 << 8) + w2] =
        __floats2half2_rn(m2[o6][0], m2[o6][1]);
  }
}

// ---------------------------------------------------------------------------
// Merged stage B (blocks 0..1535) + stage C (blocks 1536..6143).
// B phase 1 widened: 4 quarter-col outputs per unit (8 float4 -> 8 LDS cols).
// ---------------------------------------------------------------------------
#define B_STRIDE 36

__global__ __launch_bounds__(256) void k_fused_bc(
    const float* __restrict__ s0, const __half* __restrict__ pb,
    const float* __restrict__ h0a, const float* __restrict__ h0b,
    const float* __restrict__ h1a, const float* __restrict__ h1b,
    const float* __restrict__ h0, const float* __restrict__ h1,
    float* __restrict__ out) {
  __shared__ float smem[5760];  // B: 2x 80*36=5760; C: 2x 38*68=5168
  int tid = threadIdx.x;
  constexpr int spo = 128 * 128;

  if (blockIdx.x < 1536) {
    // ---------------- Stage B ----------------
    constexpr int H = 512, W = 512;
    float* lo2_s = smem;          // [80][36]
    float* hi2_s = smem + 2880;
    int p = blockIdx.x >> 6;
    int tloc = blockIdx.x & 63;
    int th = tloc >> 3, tw = tloc & 7;
    int h4_0 = th << 4, w4_0 = tw << 4;
    const float* sp = s0 + (size_t)p * (H * W);
    float fa0[10], fb0[10], fa1[10], fb1[10];
#pragma unroll
    for (int j = 0; j < 10; ++j) {
      fa0[j] = h0a[j]; fb0[j] = h0b[j]; fa1[j] = h1a[j]; fb1[j] = h1b[j];
    }

    // Phase 1: row dfilt -> LDS; 4 quarter-cols (8 outputs) from 8 float4s
    for (int e = tid; e < 80 * 4; e += 256) {
      int hr = e >> 2, gg = e & 3;
      int row = refl((h4_0 << 2) - 8 + hr, H);
      const float* xr = sp + (size_t)row * W;
      int i0 = w4_0 + (gg << 2);
      int base = (i0 << 2) - 8;
      float v[32];
      if (base >= 0 && base + 32 <= W) {
        const float* xb = xr + base;
#pragma unroll
        for (int q = 0; q < 8; ++q) {
          float4 t = *(const float4*)(xb + (q << 2));
          v[4 * q] = t.x; v[4 * q + 1] = t.y; v[4 * q + 2] = t.z; v[4 * q + 3] = t.w;
        }
      } else {
#pragma unroll
        for (int t = 0; t < 32; ++t) v[t] = xr[refl(base + t, W)];
      }
      float r0[8], r1[8];
#pragma unroll
      for (int k = 0; k < 4; ++k) {
        float ya0 = 0.f, yb0 = 0.f, ya1 = 0.f, yb1 = 0.f;
#pragma unroll
        for (int j = 0; j < 10; ++j) {
          float ve = v[4 * k + 2 * j], vo = v[4 * k + 2 * j + 1];
          ya0 += fa0[j] * ve; yb0 += fb0[j] * vo;
          ya1 += fa1[j] * ve; yb1 += fb1[j] * vo;
        }
        r0[2 * k] = ya0; r0[2 * k + 1] = yb0;
        r1[2 * k] = yb1; r1[2 * k + 1] = ya1;  // highpass: first=yb
      }
      *(float4*)&lo2_s[hr * B_STRIDE + (gg << 3)] = make_float4(r0[0], r0[1], r0[2], r0[3]);
      *(float4*)&lo2_s[hr * B_STRIDE + (gg << 3) + 4] = make_float4(r0[4], r0[5], r0[6], r0[7]);
      *(float4*)&hi2_s[hr * B_STRIDE + (gg << 3)] = make_float4(r1[0], r1[1], r1[2], r1[3]);
      *(float4*)&hi2_s[hr * B_STRIDE + (gg << 3) + 4] = make_float4(r1[4], r1[5], r1[6], r1[7]);
    }
    __syncthreads();

    // Phase 2: col dfilt + q2c + mag + pooled ll (1 output/thread)
    int h4l = tid >> 4, w4l = tid & 15;
    int h4 = h4_0 + h4l, w4 = w4_0 + w4l;
    int cl = w4l << 1;
    float a0l[2] = {0.f, 0.f}, b0l[2] = {0.f, 0.f}, a1l[2] = {0.f, 0.f}, b1l[2] = {0.f, 0.f};
    float a0h[2] = {0.f, 0.f}, b0h[2] = {0.f, 0.f}, a1h[2] = {0.f, 0.f}, b1h[2] = {0.f, 0.f};
#pragma unroll
    for (int j = 0; j < 10; ++j) {
      int hre = (h4l << 2) + 2 * j;
      float2 le = *(const float2*)&lo2_s[hre * B_STRIDE + cl];
      float2 lo_ = *(const float2*)&lo2_s[(hre + 1) * B_STRIDE + cl];
      float2 he = *(const float2*)&hi2_s[hre * B_STRIDE + cl];
      float2 ho = *(const float2*)&hi2_s[(hre + 1) * B_STRIDE + cl];
      a0l[0] += fa0[j] * le.x;  a0l[1] += fa0[j] * le.y;
      b0l[0] += fb0[j] * lo_.x; b0l[1] += fb0[j] * lo_.y;
      a1l[0] += fa1[j] * le.x;  a1l[1] += fa1[j] * le.y;
      b1l[0] += fb1[j] * lo_.x; b1l[1] += fb1[j] * lo_.y;
      a0h[0] += fa0[j] * he.x;  a0h[1] += fa0[j] * he.y;
      b0h[0] += fb0[j] * ho.x;  b0h[1] += fb0[j] * ho.y;
      a1h[0] += fa1[j] * he.x;  a1h[1] += fa1[j] * he.y;
      b1h[0] += fb1[j] * ho.x;  b1h[1] += fb1[j] * ho.y;
    }
    float llv[2][2], lhv[2][2], hlv[2][2], hhv[2][2];
#pragma unroll
    for (int dc = 0; dc < 2; ++dc) {
      llv[0][dc] = a0l[dc]; llv[1][dc] = b0l[dc];
      lhv[0][dc] = b1l[dc]; lhv[1][dc] = a1l[dc];
      hlv[0][dc] = a0h[dc]; hlv[1][dc] = b0h[dc];
      hhv[0][dc] = b1h[dc]; hhv[1][dc] = a1h[dc];
    }
    int n = p / 3, ch = p - 3 * n;
    float* ob = out + (size_t)n * 147 * spo + ((size_t)h4 << 7) + w4;
    ob[(size_t)ch * spo] = 0.25f * (llv[0][0] + llv[0][1] + llv[1][0] + llv[1][1]);
    float m[6];
    { float a = lhv[0][0], b = lhv[0][1], c = lhv[1][0], d = lhv[1][1];
      m[0] = magf((a + d) * 0.5f, (b - c) * 0.5f);
      m[5] = magf((a - d) * 0.5f, (b + c) * 0.5f); }
    { float a = hhv[0][0], b = hhv[0][1], c = hhv[1][0], d = hhv[1][1];
      m[1] = magf((a + d) * 0.5f, (b - c) * 0.5f);
      m[4] = magf((a - d) * 0.5f, (b + c) * 0.5f); }
    { float a = hlv[0][0], b = hlv[0][1], c = hlv[1][0], d = hlv[1][1];
      m[2] = magf((a + d) * 0.5f, (b - c) * 0.5f);
      m[3] = magf((a - d) * 0.5f, (b + c) * 0.5f); }
#pragma unroll
    for (int o = 0; o < 6; ++o) {
      ob[(size_t)((7 + o) * 3 + ch) * spo] = m[o];
    }
  } else {
    // ---------------- Stage C (pb fp16, 144x256x256) ----------------
    constexpr int H = 256, W = 256;
    float* lo_s = smem;           // [38][68]
    float* hi_s = smem + 2584;
    int bid = blockIdx.x - 1536;
    int p = bid >> 5;             // 32 tiles/plane
    int tloc = bid & 31;
    int th = tloc >> 2, tw = tloc & 3;  // 8 x 4 tiles
    int h2_0 = th << 4, w2_0 = tw << 5;
    int c0 = w2_0 << 1;
    const __half* xp = pb + (size_t)p * (H * W);
    float f0[5], f1[7];
#pragma unroll
    for (int j = 0; j < 5; ++j) f0[j] = h0[j];
#pragma unroll
    for (int j = 0; j < 7; ++j) f1[j] = h1[j];

    // Phase 1: fp16 row filter -> LDS (38 rows x 8 groups of 8 cols)
    for (int e = tid; e < 38 * 8; e += 256) {
      int r = e >> 3, g = e & 7;
      int row = refl((h2_0 << 1) - 3 + r, H);
      const __half* xr = xp + (size_t)row * W;
      int cb = c0 + (g << 3);
      float v[16];
      if (cb >= 4 && cb + 12 <= W) {
        union { uint2 u; __half2 h[2]; } q0, q1, q2, q3;
        q0.u = *(const uint2*)(xr + cb - 4);
        q1.u = *(const uint2*)(xr + cb);
        q2.u = *(const uint2*)(xr + cb + 4);
        q3.u = *(const uint2*)(xr + cb + 8);
        float2 t;
        t = __half22float2(q0.h[0]); v[0] = t.x; v[1] = t.y;
        t = __half22float2(q0.h[1]); v[2] = t.x; v[3] = t.y;
        t = __half22float2(q1.h[0]); v[4] = t.x; v[5] = t.y;
        t = __half22float2(q1.h[1]); v[6] = t.x; v[7] = t.y;
        t = __half22float2(q2.h[0]); v[8] = t.x; v[9] = t.y;
        t = __half22float2(q2.h[1]); v[10] = t.x; v[11] = t.y;
        t = __half22float2(q3.h[0]); v[12] = t.x; v[13] = t.y;
        t = __half22float2(q3.h[1]); v[14] = t.x; v[15] = t.y;
      } else {
        v[0] = 0.f; v[15] = 0.f;
#pragma unroll
        for (int t2 = 1; t2 <= 14; ++t2) v[t2] = __half2float(xr[refl(cb - 4 + t2, W)]);
      }
      float o0[8], o1[8];
      filt8_win(v, f0, f1, o0, o1);
      *(float4*)&lo_s[r * J1_STRIDE + (g << 3)] = make_float4(o0[0], o0[1], o0[2], o0[3]);
      *(float4*)&lo_s[r * J1_STRIDE + (g << 3) + 4] = make_float4(o0[4], o0[5], o0[6], o0[7]);
      *(float4*)&hi_s[r * J1_STRIDE + (g << 3)] = make_float4(o1[0], o1[1], o1[2], o1[3]);
      *(float4*)&hi_s[r * J1_STRIDE + (g << 3) + 4] = make_float4(o1[4], o1[5], o1[6], o1[7]);
    }
    __syncthreads();

    int c18 = p % 18, n = p / 18;
    int o1i = c18 / 3, ch = c18 - 3 * o1i;
    float* ob = out + (size_t)n * 147 * spo;
    int hq = tid >> 4, wq = tid & 15;
    int h2 = h2_0 + hq;
    int w2 = w2_0 + (wq << 1);
    J1Acc A;
    j1_colfilt4(lo_s, hi_s, hq << 1, wq << 2, f0, f1, &A);
    size_t px = ((size_t)h2 << 7) + w2;
    float pl0 = 0.25f * (A.ll[0][0] + A.ll[0][1] + A.ll[1][0] + A.ll[1][1]);
    float pl1 = 0.25f * (A.ll[0][2] + A.ll[0][3] + A.ll[1][2] + A.ll[1][3]);
    *(float2*)&ob[(size_t)((1 + o1i) * 3 + ch) * spo + px] = make_float2(pl0, pl1);
    float m2[6][2];
#pragma unroll
    for (int k = 0; k < 2; ++k) {
      q2c_mag_k(A.lh, k, &m2[0][k], &m2[5][k]);
      q2c_mag_k(A.hh, k, &m2[1][k], &m2[4][k]);
      q2c_mag_k(A.hl, k, &m2[2][k], &m2[3][k]);
    }
#pragma unroll
    for (int o2 = 0; o2 < 6; ++o2) {
      *(float2*)&ob[(size_t)((13 + o2 * 6 + o1i) * 3 + ch) * spo + px] =
          make_float2(m2[o2][0], m2[o2][1]);
    }
  }
}

extern "C" void kernel_launch(void* const* d_in, const int* in_sizes, int n_in,
                              void* d_out, int out_size, void* d_ws, size_t ws_size,
                              hipStream_t stream) {
  const float* x   = (const float*)d_in[0];
  const float* h0o = (const float*)d_in[1];
  const float* h1o = (const float*)d_in[2];
  const float* h0a = (const float*)d_in[3];
  const float* h0b = (const float*)d_in[4];
  const float* h1a = (const float*)d_in[5];
  const float* h1b = (const float*)d_in[6];
  float* out = (float*)d_out;
  char* ws = (char*)d_ws;
  (void)in_sizes; (void)n_in; (void)out_size; (void)ws_size;

  // Workspace: s0 f32 (24x512x512 = 24 MB), pb fp16 (8x18x256x256 = 18.9 MB)
  const size_t SZ_S0 = (size_t)24 * 512 * 512 * sizeof(float);
  float* s0 = (float*)ws;
  __half* pb = (__half*)(ws + SZ_S0);

  k_fused_j1a<<<3072, 256, 0, stream>>>(x, h0o, h1o, s0, pb);
  k_fused_bc<<<6144, 256, 0, stream>>>(s0, pb, h0a, h0b, h1a, h1b, h0o, h1o, out);
}

// Round 14
// 59.626 us; speedup vs baseline: 1.0856x; 1.0093x over previous
//
#include <hip/hip_runtime.h>
#include <hip/hip_fp16.h>
#include <math.h>

#define MAGB 0.01f

typedef float f2vec __attribute__((ext_vector_type(2)));

__device__ __forceinline__ void nt_store_f(float* p, float v) {
  __builtin_nontemporal_store(v, p);
}
__device__ __forceinline__ void nt_store_f2(float* p, float a, float b) {
  f2vec v; v.x = a; v.y = b;
  __builtin_nontemporal_store(v, (f2vec*)p);
}

__device__ __forceinline__ int refl(int i, int n) {
  if (i < 0) i = -1 - i;
  if (i >= n) i = 2 * n - 1 - i;
  return i;
}

__device__ __forceinline__ float magf(float re, float im) {
  return sqrtf(re * re + im * im + MAGB * MAGB) - MAGB;
}

// 16-wide window v[0..15] (cols cb-4..cb+11) -> 8 outputs (cols cb..cb+7)
__device__ __forceinline__ void filt8_win(const float* __restrict__ v,
                                          const float* __restrict__ f0,
                                          const float* __restrict__ f1,
                                          float* o0, float* o1) {
#pragma unroll
  for (int k = 0; k < 8; ++k) {
    float a0 = 0.f, a1 = 0.f;
#pragma unroll
    for (int j = 0; j < 5; ++j) a0 += f0[j] * v[k + 2 + j];
#pragma unroll
    for (int j = 0; j < 7; ++j) a1 += f1[j] * v[k + 1 + j];
    o0[k] = a0; o1[k] = a1;
  }
}

#define J1_STRIDE 68

// j1 column filter: 8-row window over 4 LDS columns -> ll/lh/hl/hh [dr][4]
struct J1Acc {
  float ll[2][4], lh[2][4], hl[2][4], hh[2][4];
};

__device__ __forceinline__ void j1_colfilt4(
    const float* __restrict__ lo_s, const float* __restrict__ hi_s,
    int row0, int col, const float* __restrict__ f0, const float* __restrict__ f1,
    J1Acc* A) {
#pragma unroll
  for (int dr = 0; dr < 2; ++dr)
#pragma unroll
    for (int c = 0; c < 4; ++c) {
      A->ll[dr][c] = 0.f; A->lh[dr][c] = 0.f; A->hl[dr][c] = 0.f; A->hh[dr][c] = 0.f;
    }
#pragma unroll
  for (int tt = 0; tt < 8; ++tt) {
    float4 lv4 = *(const float4*)(lo_s + (row0 + tt) * J1_STRIDE + col);
    float4 hv4 = *(const float4*)(hi_s + (row0 + tt) * J1_STRIDE + col);
    float lv[4] = {lv4.x, lv4.y, lv4.z, lv4.w};
    float hv[4] = {hv4.x, hv4.y, hv4.z, hv4.w};
#pragma unroll
    for (int dr = 0; dr < 2; ++dr) {
      int j0 = tt - dr - 1;  // 5-tap index
      int j1 = tt - dr;      // 7-tap index
#pragma unroll
      for (int c = 0; c < 4; ++c) {
        if (j0 >= 0 && j0 < 5) {
          A->ll[dr][c] += f0[j0] * lv[c];
          A->hl[dr][c] += f0[j0] * hv[c];
        }
        if (j1 >= 0 && j1 < 7) {
          A->lh[dr][c] += f1[j1] * lv[c];
          A->hh[dr][c] += f1[j1] * hv[c];
        }
      }
    }
  }
}

__device__ __forceinline__ void q2c_mag_k(const float v[2][4], int k,
                                          float* mlo, float* mhi) {
  float a = v[0][2 * k], b = v[0][2 * k + 1], c = v[1][2 * k], d = v[1][2 * k + 1];
  *mlo = magf((a + d) * 0.5f, (b - c) * 0.5f);
  *mhi = magf((a - d) * 0.5f, (b + c) * 0.5f);
}

// ---------------------------------------------------------------------------
// Stage A: fused j1 on x (8,3,512,512). Tile half-res 16x32 (full 32x64).
// Phase 1: 8-wide units (38 rows x 8 groups). Writes s0 (f32) + pb (fp16).
// ---------------------------------------------------------------------------
__global__ __launch_bounds__(256) void k_fused_j1a(
    const float* __restrict__ x,
    const float* __restrict__ h0, const float* __restrict__ h1,
    float* __restrict__ s0, __half* __restrict__ pb) {
  constexpr int H = 512, W = 512;
  __shared__ float lo_s[38 * J1_STRIDE];
  __shared__ float hi_s[38 * J1_STRIDE];
  int p = blockIdx.x >> 7;            // 128 tiles/plane
  int tloc = blockIdx.x & 127;
  int th = tloc >> 3, tw = tloc & 7;  // 16 x 8 tiles
  int h2_0 = th << 4, w2_0 = tw << 5;
  int c0 = w2_0 << 1;
  const float* xp = x + (size_t)p * (H * W);
  float f0[5], f1[7];
#pragma unroll
  for (int j = 0; j < 5; ++j) f0[j] = h0[j];
#pragma unroll
  for (int j = 0; j < 7; ++j) f1[j] = h1[j];
  int tid = threadIdx.x;

  // Phase 1: row filter -> LDS (38 rows x 8 groups of 8 cols)
  for (int e = tid; e < 38 * 8; e += 256) {
    int r = e >> 3, g = e & 7;
    int row = refl((h2_0 << 1) - 3 + r, H);
    const float* xr = xp + (size_t)row * W;
    int cb = c0 + (g << 3);
    float v[16];
    if (cb >= 4 && cb + 12 <= W) {
      float4 q0 = *(const float4*)(xr + cb - 4);
      float4 q1 = *(const float4*)(xr + cb);
      float4 q2 = *(const float4*)(xr + cb + 4);
      float4 q3 = *(const float4*)(xr + cb + 8);
      v[0] = q0.x; v[1] = q0.y; v[2] = q0.z; v[3] = q0.w;
      v[4] = q1.x; v[5] = q1.y; v[6] = q1.z; v[7] = q1.w;
      v[8] = q2.x; v[9] = q2.y; v[10] = q2.z; v[11] = q2.w;
      v[12] = q3.x; v[13] = q3.y; v[14] = q3.z; v[15] = q3.w;
    } else {
      v[0] = 0.f; v[15] = 0.f;
#pragma unroll
      for (int t = 1; t <= 14; ++t) v[t] = xr[refl(cb - 4 + t, W)];
    }
    float o0[8], o1[8];
    filt8_win(v, f0, f1, o0, o1);
    *(float4*)&lo_s[r * J1_STRIDE + (g << 3)] = make_float4(o0[0], o0[1], o0[2], o0[3]);
    *(float4*)&lo_s[r * J1_STRIDE + (g << 3) + 4] = make_float4(o0[4], o0[5], o0[6], o0[7]);
    *(float4*)&hi_s[r * J1_STRIDE + (g << 3)] = make_float4(o1[0], o1[1], o1[2], o1[3]);
    *(float4*)&hi_s[r * J1_STRIDE + (g << 3) + 4] = make_float4(o1[4], o1[5], o1[6], o1[7]);
  }
  __syncthreads();

  // Phase 2: one output-pair per thread (16 hq x 16 w-pairs)
  int n = p / 3, ch = p - 3 * n;
  float* s0p = s0 + (size_t)p * (H * W);
  constexpr int sp2 = 256 * 256;
  __half* pbb = pb + (size_t)n * 18 * sp2;
  int hq = tid >> 4, wq = tid & 15;
  int h2 = h2_0 + hq;
  int w2 = w2_0 + (wq << 1);
  J1Acc A;
  j1_colfilt4(lo_s, hi_s, hq << 1, wq << 2, f0, f1, &A);
#pragma unroll
  for (int dr = 0; dr < 2; ++dr) {
    *(float4*)&s0p[(size_t)((h2 << 1) + dr) * W + (w2 << 1)] =
        make_float4(A.ll[dr][0], A.ll[dr][1], A.ll[dr][2], A.ll[dr][3]);
  }
  float m2[6][2];
#pragma unroll
  for (int k = 0; k < 2; ++k) {
    q2c_mag_k(A.lh, k, &m2[0][k], &m2[5][k]);
    q2c_mag_k(A.hh, k, &m2[1][k], &m2[4][k]);
    q2c_mag_k(A.hl, k, &m2[2][k], &m2[3][k]);
  }
#pragma unroll
  for (int o6 = 0; o6 < 6; ++o6) {
    *(__half2*)&pbb[(size_t)(o6 * 3 + ch) * sp2 + (h2 << 8) + w2] =
        __floats2half2_rn(m2[o6][0], m2[o6][1]);
  }
}

// ---------------------------------------------------------------------------
// Merged stage B (blocks 0..1535) + stage C (blocks 1536..6143).
// out written with non-temporal stores (write-once stream).
// ---------------------------------------------------------------------------
#define B_STRIDE 36

__global__ __launch_bounds__(256) void k_fused_bc(
    const float* __restrict__ s0, const __half* __restrict__ pb,
    const float* __restrict__ h0a, const float* __restrict__ h0b,
    const float* __restrict__ h1a, const float* __restrict__ h1b,
    const float* __restrict__ h0, const float* __restrict__ h1,
    float* __restrict__ out) {
  __shared__ float smem[5760];  // B: 2x 80*36=5760; C: 2x 38*68=5168
  int tid = threadIdx.x;
  constexpr int spo = 128 * 128;

  if (blockIdx.x < 1536) {
    // ---------------- Stage B ----------------
    constexpr int H = 512, W = 512;
    float* lo2_s = smem;          // [80][36]
    float* hi2_s = smem + 2880;
    int p = blockIdx.x >> 6;
    int tloc = blockIdx.x & 63;
    int th = tloc >> 3, tw = tloc & 7;
    int h4_0 = th << 4, w4_0 = tw << 4;
    const float* sp = s0 + (size_t)p * (H * W);
    float fa0[10], fb0[10], fa1[10], fb1[10];
#pragma unroll
    for (int j = 0; j < 10; ++j) {
      fa0[j] = h0a[j]; fb0[j] = h0b[j]; fa1[j] = h1a[j]; fb1[j] = h1b[j];
    }

    // Phase 1: row dfilt -> LDS; 4 quarter-cols (8 outputs) from 8 float4s
    for (int e = tid; e < 80 * 4; e += 256) {
      int hr = e >> 2, gg = e & 3;
      int row = refl((h4_0 << 2) - 8 + hr, H);
      const float* xr = sp + (size_t)row * W;
      int i0 = w4_0 + (gg << 2);
      int base = (i0 << 2) - 8;
      float v[32];
      if (base >= 0 && base + 32 <= W) {
        const float* xb = xr + base;
#pragma unroll
        for (int q = 0; q < 8; ++q) {
          float4 t = *(const float4*)(xb + (q << 2));
          v[4 * q] = t.x; v[4 * q + 1] = t.y; v[4 * q + 2] = t.z; v[4 * q + 3] = t.w;
        }
      } else {
#pragma unroll
        for (int t = 0; t < 32; ++t) v[t] = xr[refl(base + t, W)];
      }
      float r0[8], r1[8];
#pragma unroll
      for (int k = 0; k < 4; ++k) {
        float ya0 = 0.f, yb0 = 0.f, ya1 = 0.f, yb1 = 0.f;
#pragma unroll
        for (int j = 0; j < 10; ++j) {
          float ve = v[4 * k + 2 * j], vo = v[4 * k + 2 * j + 1];
          ya0 += fa0[j] * ve; yb0 += fb0[j] * vo;
          ya1 += fa1[j] * ve; yb1 += fb1[j] * vo;
        }
        r0[2 * k] = ya0; r0[2 * k + 1] = yb0;
        r1[2 * k] = yb1; r1[2 * k + 1] = ya1;  // highpass: first=yb
      }
      *(float4*)&lo2_s[hr * B_STRIDE + (gg << 3)] = make_float4(r0[0], r0[1], r0[2], r0[3]);
      *(float4*)&lo2_s[hr * B_STRIDE + (gg << 3) + 4] = make_float4(r0[4], r0[5], r0[6], r0[7]);
      *(float4*)&hi2_s[hr * B_STRIDE + (gg << 3)] = make_float4(r1[0], r1[1], r1[2], r1[3]);
      *(float4*)&hi2_s[hr * B_STRIDE + (gg << 3) + 4] = make_float4(r1[4], r1[5], r1[6], r1[7]);
    }
    __syncthreads();

    // Phase 2: col dfilt + q2c + mag + pooled ll (1 output/thread)
    int h4l = tid >> 4, w4l = tid & 15;
    int h4 = h4_0 + h4l, w4 = w4_0 + w4l;
    int cl = w4l << 1;
    float a0l[2] = {0.f, 0.f}, b0l[2] = {0.f, 0.f}, a1l[2] = {0.f, 0.f}, b1l[2] = {0.f, 0.f};
    float a0h[2] = {0.f, 0.f}, b0h[2] = {0.f, 0.f}, a1h[2] = {0.f, 0.f}, b1h[2] = {0.f, 0.f};
#pragma unroll
    for (int j = 0; j < 10; ++j) {
      int hre = (h4l << 2) + 2 * j;
      float2 le = *(const float2*)&lo2_s[hre * B_STRIDE + cl];
      float2 lo_ = *(const float2*)&lo2_s[(hre + 1) * B_STRIDE + cl];
      float2 he = *(const float2*)&hi2_s[hre * B_STRIDE + cl];
      float2 ho = *(const float2*)&hi2_s[(hre + 1) * B_STRIDE + cl];
      a0l[0] += fa0[j] * le.x;  a0l[1] += fa0[j] * le.y;
      b0l[0] += fb0[j] * lo_.x; b0l[1] += fb0[j] * lo_.y;
      a1l[0] += fa1[j] * le.x;  a1l[1] += fa1[j] * le.y;
      b1l[0] += fb1[j] * lo_.x; b1l[1] += fb1[j] * lo_.y;
      a0h[0] += fa0[j] * he.x;  a0h[1] += fa0[j] * he.y;
      b0h[0] += fb0[j] * ho.x;  b0h[1] += fb0[j] * ho.y;
      a1h[0] += fa1[j] * he.x;  a1h[1] += fa1[j] * he.y;
      b1h[0] += fb1[j] * ho.x;  b1h[1] += fb1[j] * ho.y;
    }
    float llv[2][2], lhv[2][2], hlv[2][2], hhv[2][2];
#pragma unroll
    for (int dc = 0; dc < 2; ++dc) {
      llv[0][dc] = a0l[dc]; llv[1][dc] = b0l[dc];
      lhv[0][dc] = b1l[dc]; lhv[1][dc] = a1l[dc];
      hlv[0][dc] = a0h[dc]; hlv[1][dc] = b0h[dc];
      hhv[0][dc] = b1h[dc]; hhv[1][dc] = a1h[dc];
    }
    int n = p / 3, ch = p - 3 * n;
    float* ob = out + (size_t)n * 147 * spo + ((size_t)h4 << 7) + w4;
    nt_store_f(&ob[(size_t)ch * spo],
               0.25f * (llv[0][0] + llv[0][1] + llv[1][0] + llv[1][1]));
    float m[6];
    { float a = lhv[0][0], b = lhv[0][1], c = lhv[1][0], d = lhv[1][1];
      m[0] = magf((a + d) * 0.5f, (b - c) * 0.5f);
      m[5] = magf((a - d) * 0.5f, (b + c) * 0.5f); }
    { float a = hhv[0][0], b = hhv[0][1], c = hhv[1][0], d = hhv[1][1];
      m[1] = magf((a + d) * 0.5f, (b - c) * 0.5f);
      m[4] = magf((a - d) * 0.5f, (b + c) * 0.5f); }
    { float a = hlv[0][0], b = hlv[0][1], c = hlv[1][0], d = hlv[1][1];
      m[2] = magf((a + d) * 0.5f, (b - c) * 0.5f);
      m[3] = magf((a - d) * 0.5f, (b + c) * 0.5f); }
#pragma unroll
    for (int o = 0; o < 6; ++o) {
      nt_store_f(&ob[(size_t)((7 + o) * 3 + ch) * spo], m[o]);
    }
  } else {
    // ---------------- Stage C (pb fp16, 144x256x256) ----------------
    constexpr int H = 256, W = 256;
    float* lo_s = smem;           // [38][68]
    float* hi_s = smem + 2584;
    int bid = blockIdx.x - 1536;
    int p = bid >> 5;             // 32 tiles/plane
    int tloc = bid & 31;
    int th = tloc >> 2, tw = tloc & 3;  // 8 x 4 tiles
    int h2_0 = th << 4, w2_0 = tw << 5;
    int c0 = w2_0 << 1;
    const __half* xp = pb + (size_t)p * (H * W);
    float f0[5], f1[7];
#pragma unroll
    for (int j = 0; j < 5; ++j) f0[j] = h0[j];
#pragma unroll
    for (int j = 0; j < 7; ++j) f1[j] = h1[j];

    // Phase 1: fp16 row filter -> LDS (38 rows x 8 groups of 8 cols)
    for (int e = tid; e < 38 * 8; e += 256) {
      int r = e >> 3, g = e & 7;
      int row = refl((h2_0 << 1) - 3 + r, H);
      const __half* xr = xp + (size_t)row * W;
      int cb = c0 + (g << 3);
      float v[16];
      if (cb >= 4 && cb + 12 <= W) {
        union { uint2 u; __half2 h[2]; } q0, q1, q2, q3;
        q0.u = *(const uint2*)(xr + cb - 4);
        q1.u = *(const uint2*)(xr + cb);
        q2.u = *(const uint2*)(xr + cb + 4);
        q3.u = *(const uint2*)(xr + cb + 8);
        float2 t;
        t = __half22float2(q0.h[0]); v[0] = t.x; v[1] = t.y;
        t = __half22float2(q0.h[1]); v[2] = t.x; v[3] = t.y;
        t = __half22float2(q1.h[0]); v[4] = t.x; v[5] = t.y;
        t = __half22float2(q1.h[1]); v[6] = t.x; v[7] = t.y;
        t = __half22float2(q2.h[0]); v[8] = t.x; v[9] = t.y;
        t = __half22float2(q2.h[1]); v[10] = t.x; v[11] = t.y;
        t = __half22float2(q3.h[0]); v[12] = t.x; v[13] = t.y;
        t = __half22float2(q3.h[1]); v[14] = t.x; v[15] = t.y;
      } else {
        v[0] = 0.f; v[15] = 0.f;
#pragma unroll
        for (int t2 = 1; t2 <= 14; ++t2) v[t2] = __half2float(xr[refl(cb - 4 + t2, W)]);
      }
      float o0[8], o1[8];
      filt8_win(v, f0, f1, o0, o1);
      *(float4*)&lo_s[r * J1_STRIDE + (g << 3)] = make_float4(o0[0], o0[1], o0[2], o0[3]);
      *(float4*)&lo_s[r * J1_STRIDE + (g << 3) + 4] = make_float4(o0[4], o0[5], o0[6], o0[7]);
      *(float4*)&hi_s[r * J1_STRIDE + (g << 3)] = make_float4(o1[0], o1[1], o1[2], o1[3]);
      *(float4*)&hi_s[r * J1_STRIDE + (g << 3) + 4] = make_float4(o1[4], o1[5], o1[6], o1[7]);
    }
    __syncthreads();

    int c18 = p % 18, n = p / 18;
    int o1i = c18 / 3, ch = c18 - 3 * o1i;
    float* ob = out + (size_t)n * 147 * spo;
    int hq = tid >> 4, wq = tid & 15;
    int h2 = h2_0 + hq;
    int w2 = w2_0 + (wq << 1);
    J1Acc A;
    j1_colfilt4(lo_s, hi_s, hq << 1, wq << 2, f0, f1, &A);
    size_t px = ((size_t)h2 << 7) + w2;
    float pl0 = 0.25f * (A.ll[0][0] + A.ll[0][1] + A.ll[1][0] + A.ll[1][1]);
    float pl1 = 0.25f * (A.ll[0][2] + A.ll[0][3] + A.ll[1][2] + A.ll[1][3]);
    nt_store_f2(&ob[(size_t)((1 + o1i) * 3 + ch) * spo + px], pl0, pl1);
    float m2[6][2];
#pragma unroll
    for (int k = 0; k < 2; ++k) {
      q2c_mag_k(A.lh, k, &m2[0][k], &m2[5][k]);
      q2c_mag_k(A.hh, k, &m2[1][k], &m2[4][k]);
      q2c_mag_k(A.hl, k, &m2[2][k], &m2[3][k]);
    }
#pragma unroll
    for (int o2 = 0; o2 < 6; ++o2) {
      nt_store_f2(&ob[(size_t)((13 + o2 * 6 + o1i) * 3 + ch) * spo + px],
                  m2[o2][0], m2[o2][1]);
    }
  }
}

extern "C" void kernel_launch(void* const* d_in, const int* in_sizes, int n_in,
                              void* d_out, int out_size, void* d_ws, size_t ws_size,
                              hipStream_t stream) {
  const float* x   = (const float*)d_in[0];
  const float* h0o = (const float*)d_in[1];
  const float* h1o = (const float*)d_in[2];
  const float* h0a = (const float*)d_in[3];
  const float* h0b = (const float*)d_in[4];
  const float* h1a = (const float*)d_in[5];
  const float* h1b = (const float*)d_in[6];
  float* out = (float*)d_out;
  char* ws = (char*)d_ws;
  (void)in_sizes; (void)n_in; (void)out_size; (void)ws_size;

  // Workspace: s0 f32 (24x512x512 = 24 MB), pb fp16 (8x18x256x256 = 18.9 MB)
  const size_t SZ_S0 = (size_t)24 * 512 * 512 * sizeof(float);
  float* s0 = (float*)ws;
  __half* pb = (__half*)(ws + SZ_S0);

  k_fused_j1a<<<3072, 256, 0, stream>>>(x, h0o, h1o, s0, pb);
  k_fused_bc<<<6144, 256, 0, stream>>>(s0, pb, h0a, h0b, h1a, h1b, h0o, h1o, out);
}

// Round 15
// 59.248 us; speedup vs baseline: 1.0925x; 1.0064x over previous
//
#include <hip/hip_runtime.h>
#include <hip/hip_fp16.h>
#include <math.h>

#define MAGB 0.01f

typedef float f2vec __attribute__((ext_vector_type(2)));

__device__ __forceinline__ void nt_store_f(float* p, float v) {
  __builtin_nontemporal_store(v, p);
}
__device__ __forceinline__ void nt_store_f2(float* p, float a, float b) {
  f2vec v; v.x = a; v.y = b;
  __builtin_nontemporal_store(v, (f2vec*)p);
}

// wave-uniform load -> SGPR
__device__ __forceinline__ float uload(const float* p) {
  return __uint_as_float(__builtin_amdgcn_readfirstlane(__float_as_uint(*p)));
}

__device__ __forceinline__ int refl(int i, int n) {
  if (i < 0) i = -1 - i;
  if (i >= n) i = 2 * n - 1 - i;
  return i;
}

__device__ __forceinline__ float magf(float re, float im) {
  return sqrtf(re * re + im * im + MAGB * MAGB) - MAGB;
}

// 16-wide window v[0..15] (cols cb-4..cb+11) -> 8 outputs (cols cb..cb+7)
__device__ __forceinline__ void filt8_win(const float* __restrict__ v,
                                          const float* __restrict__ f0,
                                          const float* __restrict__ f1,
                                          float* o0, float* o1) {
#pragma unroll
  for (int k = 0; k < 8; ++k) {
    float a0 = 0.f, a1 = 0.f;
#pragma unroll
    for (int j = 0; j < 5; ++j) a0 += f0[j] * v[k + 2 + j];
#pragma unroll
    for (int j = 0; j < 7; ++j) a1 += f1[j] * v[k + 1 + j];
    o0[k] = a0; o1[k] = a1;
  }
}

#define J1_STRIDE 68

// j1 column filter: 8-row window over 4 LDS columns -> ll/lh/hl/hh [dr][4]
struct J1Acc {
  float ll[2][4], lh[2][4], hl[2][4], hh[2][4];
};

__device__ __forceinline__ void j1_colfilt4(
    const float* __restrict__ lo_s, const float* __restrict__ hi_s,
    int row0, int col, const float* __restrict__ f0, const float* __restrict__ f1,
    J1Acc* A) {
#pragma unroll
  for (int dr = 0; dr < 2; ++dr)
#pragma unroll
    for (int c = 0; c < 4; ++c) {
      A->ll[dr][c] = 0.f; A->lh[dr][c] = 0.f; A->hl[dr][c] = 0.f; A->hh[dr][c] = 0.f;
    }
#pragma unroll
  for (int tt = 0; tt < 8; ++tt) {
    float4 lv4 = *(const float4*)(lo_s + (row0 + tt) * J1_STRIDE + col);
    float4 hv4 = *(const float4*)(hi_s + (row0 + tt) * J1_STRIDE + col);
    float lv[4] = {lv4.x, lv4.y, lv4.z, lv4.w};
    float hv[4] = {hv4.x, hv4.y, hv4.z, hv4.w};
#pragma unroll
    for (int dr = 0; dr < 2; ++dr) {
      int j0 = tt - dr - 1;  // 5-tap index
      int j1 = tt - dr;      // 7-tap index
#pragma unroll
      for (int c = 0; c < 4; ++c) {
        if (j0 >= 0 && j0 < 5) {
          A->ll[dr][c] += f0[j0] * lv[c];
          A->hl[dr][c] += f0[j0] * hv[c];
        }
        if (j1 >= 0 && j1 < 7) {
          A->lh[dr][c] += f1[j1] * lv[c];
          A->hh[dr][c] += f1[j1] * hv[c];
        }
      }
    }
  }
}

__device__ __forceinline__ void q2c_mag_k(const float v[2][4], int k,
                                          float* mlo, float* mhi) {
  float a = v[0][2 * k], b = v[0][2 * k + 1], c = v[1][2 * k], d = v[1][2 * k + 1];
  *mlo = magf((a + d) * 0.5f, (b - c) * 0.5f);
  *mhi = magf((a - d) * 0.5f, (b + c) * 0.5f);
}

// ---------------------------------------------------------------------------
// Stage A: fused j1 on x (8,3,512,512). Tile half-res 16x32 (full 32x64).
// Phase 1: 8-wide units (38 rows x 8 groups). Writes s0 (f32) + pb (fp16).
// ---------------------------------------------------------------------------
__global__ __launch_bounds__(256) void k_fused_j1a(
    const float* __restrict__ x,
    const float* __restrict__ h0, const float* __restrict__ h1,
    float* __restrict__ s0, __half* __restrict__ pb) {
  constexpr int H = 512, W = 512;
  __shared__ float lo_s[38 * J1_STRIDE];
  __shared__ float hi_s[38 * J1_STRIDE];
  int p = blockIdx.x >> 7;            // 128 tiles/plane
  int tloc = blockIdx.x & 127;
  int th = tloc >> 3, tw = tloc & 7;  // 16 x 8 tiles
  int h2_0 = th << 4, w2_0 = tw << 5;
  int c0 = w2_0 << 1;
  const float* xp = x + (size_t)p * (H * W);
  float f0[5], f1[7];
#pragma unroll
  for (int j = 0; j < 5; ++j) f0[j] = uload(h0 + j);
#pragma unroll
  for (int j = 0; j < 7; ++j) f1[j] = uload(h1 + j);
  int tid = threadIdx.x;

  // Phase 1: row filter -> LDS (38 rows x 8 groups of 8 cols)
  for (int e = tid; e < 38 * 8; e += 256) {
    int r = e >> 3, g = e & 7;
    int row = refl((h2_0 << 1) - 3 + r, H);
    const float* xr = xp + (size_t)row * W;
    int cb = c0 + (g << 3);
    float v[16];
    if (cb >= 4 && cb + 12 <= W) {
      float4 q0 = *(const float4*)(xr + cb - 4);
      float4 q1 = *(const float4*)(xr + cb);
      float4 q2 = *(const float4*)(xr + cb + 4);
      float4 q3 = *(const float4*)(xr + cb + 8);
      v[0] = q0.x; v[1] = q0.y; v[2] = q0.z; v[3] = q0.w;
      v[4] = q1.x; v[5] = q1.y; v[6] = q1.z; v[7] = q1.w;
      v[8] = q2.x; v[9] = q2.y; v[10] = q2.z; v[11] = q2.w;
      v[12] = q3.x; v[13] = q3.y; v[14] = q3.z; v[15] = q3.w;
    } else {
      v[0] = 0.f; v[15] = 0.f;
#pragma unroll
      for (int t = 1; t <= 14; ++t) v[t] = xr[refl(cb - 4 + t, W)];
    }
    float o0[8], o1[8];
    filt8_win(v, f0, f1, o0, o1);
    *(float4*)&lo_s[r * J1_STRIDE + (g << 3)] = make_float4(o0[0], o0[1], o0[2], o0[3]);
    *(float4*)&lo_s[r * J1_STRIDE + (g << 3) + 4] = make_float4(o0[4], o0[5], o0[6], o0[7]);
    *(float4*)&hi_s[r * J1_STRIDE + (g << 3)] = make_float4(o1[0], o1[1], o1[2], o1[3]);
    *(float4*)&hi_s[r * J1_STRIDE + (g << 3) + 4] = make_float4(o1[4], o1[5], o1[6], o1[7]);
  }
  __syncthreads();

  // Phase 2: one output-pair per thread (16 hq x 16 w-pairs)
  int n = p / 3, ch = p - 3 * n;
  float* s0p = s0 + (size_t)p * (H * W);
  constexpr int sp2 = 256 * 256;
  __half* pbb = pb + (size_t)n * 18 * sp2;
  int hq = tid >> 4, wq = tid & 15;
  int h2 = h2_0 + hq;
  int w2 = w2_0 + (wq << 1);
  J1Acc A;
  j1_colfilt4(lo_s, hi_s, hq << 1, wq << 2, f0, f1, &A);
#pragma unroll
  for (int dr = 0; dr < 2; ++dr) {
    *(float4*)&s0p[(size_t)((h2 << 1) + dr) * W + (w2 << 1)] =
        make_float4(A.ll[dr][0], A.ll[dr][1], A.ll[dr][2], A.ll[dr][3]);
  }
  float m2[6][2];
#pragma unroll
  for (int k = 0; k < 2; ++k) {
    q2c_mag_k(A.lh, k, &m2[0][k], &m2[5][k]);
    q2c_mag_k(A.hh, k, &m2[1][k], &m2[4][k]);
    q2c_mag_k(A.hl, k, &m2[2][k], &m2[3][k]);
  }
#pragma unroll
  for (int o6 = 0; o6 < 6; ++o6) {
    *(__half2*)&pbb[(size_t)(o6 * 3 + ch) * sp2 + (h2 << 8) + w2] =
        __floats2half2_rn(m2[o6][0], m2[o6][1]);
  }
}

// ---------------------------------------------------------------------------
// Merged stage B (blocks 0..1535) + stage C (blocks 1536..6143).
// Filter taps in SGPRs via readfirstlane; out stored non-temporally.
// ---------------------------------------------------------------------------
#define B_STRIDE 36

__global__ __launch_bounds__(256) void k_fused_bc(
    const float* __restrict__ s0, const __half* __restrict__ pb,
    const float* __restrict__ h0a, const float* __restrict__ h0b,
    const float* __restrict__ h1a, const float* __restrict__ h1b,
    const float* __restrict__ h0, const float* __restrict__ h1,
    float* __restrict__ out) {
  __shared__ float smem[5760];  // B: 2x 80*36=5760; C: 2x 38*68=5168
  int tid = threadIdx.x;
  constexpr int spo = 128 * 128;

  if (blockIdx.x < 1536) {
    // ---------------- Stage B ----------------
    constexpr int H = 512, W = 512;
    float* lo2_s = smem;          // [80][36]
    float* hi2_s = smem + 2880;
    int p = blockIdx.x >> 6;
    int tloc = blockIdx.x & 63;
    int th = tloc >> 3, tw = tloc & 7;
    int h4_0 = th << 4, w4_0 = tw << 4;
    const float* sp = s0 + (size_t)p * (H * W);
    float fa0[10], fb0[10], fa1[10], fb1[10];
#pragma unroll
    for (int j = 0; j < 10; ++j) {
      fa0[j] = uload(h0a + j); fb0[j] = uload(h0b + j);
      fa1[j] = uload(h1a + j); fb1[j] = uload(h1b + j);
    }

    // Phase 1: row dfilt -> LDS; 4 quarter-cols (8 outputs) from 8 float4s
    for (int e = tid; e < 80 * 4; e += 256) {
      int hr = e >> 2, gg = e & 3;
      int row = refl((h4_0 << 2) - 8 + hr, H);
      const float* xr = sp + (size_t)row * W;
      int i0 = w4_0 + (gg << 2);
      int base = (i0 << 2) - 8;
      float v[32];
      if (base >= 0 && base + 32 <= W) {
        const float* xb = xr + base;
#pragma unroll
        for (int q = 0; q < 8; ++q) {
          float4 t = *(const float4*)(xb + (q << 2));
          v[4 * q] = t.x; v[4 * q + 1] = t.y; v[4 * q + 2] = t.z; v[4 * q + 3] = t.w;
        }
      } else {
#pragma unroll
        for (int t = 0; t < 32; ++t) v[t] = xr[refl(base + t, W)];
      }
      float r0[8], r1[8];
#pragma unroll
      for (int k = 0; k < 4; ++k) {
        float ya0 = 0.f, yb0 = 0.f, ya1 = 0.f, yb1 = 0.f;
#pragma unroll
        for (int j = 0; j < 10; ++j) {
          float ve = v[4 * k + 2 * j], vo = v[4 * k + 2 * j + 1];
          ya0 += fa0[j] * ve; yb0 += fb0[j] * vo;
          ya1 += fa1[j] * ve; yb1 += fb1[j] * vo;
        }
        r0[2 * k] = ya0; r0[2 * k + 1] = yb0;
        r1[2 * k] = yb1; r1[2 * k + 1] = ya1;  // highpass: first=yb
      }
      *(float4*)&lo2_s[hr * B_STRIDE + (gg << 3)] = make_float4(r0[0], r0[1], r0[2], r0[3]);
      *(float4*)&lo2_s[hr * B_STRIDE + (gg << 3) + 4] = make_float4(r0[4], r0[5], r0[6], r0[7]);
      *(float4*)&hi2_s[hr * B_STRIDE + (gg << 3)] = make_float4(r1[0], r1[1], r1[2], r1[3]);
      *(float4*)&hi2_s[hr * B_STRIDE + (gg << 3) + 4] = make_float4(r1[4], r1[5], r1[6], r1[7]);
    }
    __syncthreads();

    // Phase 2: col dfilt + q2c + mag + pooled ll (1 output/thread)
    int h4l = tid >> 4, w4l = tid & 15;
    int h4 = h4_0 + h4l, w4 = w4_0 + w4l;
    int cl = w4l << 1;
    float a0l[2] = {0.f, 0.f}, b0l[2] = {0.f, 0.f}, a1l[2] = {0.f, 0.f}, b1l[2] = {0.f, 0.f};
    float a0h[2] = {0.f, 0.f}, b0h[2] = {0.f, 0.f}, a1h[2] = {0.f, 0.f}, b1h[2] = {0.f, 0.f};
#pragma unroll
    for (int j = 0; j < 10; ++j) {
      int hre = (h4l << 2) + 2 * j;
      float2 le = *(const float2*)&lo2_s[hre * B_STRIDE + cl];
      float2 lo_ = *(const float2*)&lo2_s[(hre + 1) * B_STRIDE + cl];
      float2 he = *(const float2*)&hi2_s[hre * B_STRIDE + cl];
      float2 ho = *(const float2*)&hi2_s[(hre + 1) * B_STRIDE + cl];
      a0l[0] += fa0[j] * le.x;  a0l[1] += fa0[j] * le.y;
      b0l[0] += fb0[j] * lo_.x; b0l[1] += fb0[j] * lo_.y;
      a1l[0] += fa1[j] * le.x;  a1l[1] += fa1[j] * le.y;
      b1l[0] += fb1[j] * lo_.x; b1l[1] += fb1[j] * lo_.y;
      a0h[0] += fa0[j] * he.x;  a0h[1] += fa0[j] * he.y;
      b0h[0] += fb0[j] * ho.x;  b0h[1] += fb0[j] * ho.y;
      a1h[0] += fa1[j] * he.x;  a1h[1] += fa1[j] * he.y;
      b1h[0] += fb1[j] * ho.x;  b1h[1] += fb1[j] * ho.y;
    }
    float llv[2][2], lhv[2][2], hlv[2][2], hhv[2][2];
#pragma unroll
    for (int dc = 0; dc < 2; ++dc) {
      llv[0][dc] = a0l[dc]; llv[1][dc] = b0l[dc];
      lhv[0][dc] = b1l[dc]; lhv[1][dc] = a1l[dc];
      hlv[0][dc] = a0h[dc]; hlv[1][dc] = b0h[dc];
      hhv[0][dc] = b1h[dc]; hhv[1][dc] = a1h[dc];
    }
    int n = p / 3, ch = p - 3 * n;
    float* ob = out + (size_t)n * 147 * spo + ((size_t)h4 << 7) + w4;
    nt_store_f(&ob[(size_t)ch * spo],
               0.25f * (llv[0][0] + llv[0][1] + llv[1][0] + llv[1][1]));
    float m[6];
    { float a = lhv[0][0], b = lhv[0][1], c = lhv[1][0], d = lhv[1][1];
      m[0] = magf((a + d) * 0.5f, (b - c) * 0.5f);
      m[5] = magf((a - d) * 0.5f, (b + c) * 0.5f); }
    { float a = hhv[0][0], b = hhv[0][1], c = hhv[1][0], d = hhv[1][1];
      m[1] = magf((a + d) * 0.5f, (b - c) * 0.5f);
      m[4] = magf((a - d) * 0.5f, (b + c) * 0.5f); }
    { float a = hlv[0][0], b = hlv[0][1], c = hlv[1][0], d = hlv[1][1];
      m[2] = magf((a + d) * 0.5f, (b - c) * 0.5f);
      m[3] = magf((a - d) * 0.5f, (b + c) * 0.5f); }
#pragma unroll
    for (int o = 0; o < 6; ++o) {
      nt_store_f(&ob[(size_t)((7 + o) * 3 + ch) * spo], m[o]);
    }
  } else {
    // ---------------- Stage C (pb fp16, 144x256x256) ----------------
    constexpr int H = 256, W = 256;
    float* lo_s = smem;           // [38][68]
    float* hi_s = smem + 2584;
    int bid = blockIdx.x - 1536;
    int p = bid >> 5;             // 32 tiles/plane
    int tloc = bid & 31;
    int th = tloc >> 2, tw = tloc & 3;  // 8 x 4 tiles
    int h2_0 = th << 4, w2_0 = tw << 5;
    int c0 = w2_0 << 1;
    const __half* xp = pb + (size_t)p * (H * W);
    float f0[5], f1[7];
#pragma unroll
    for (int j = 0; j < 5; ++j) f0[j] = uload(h0 + j);
#pragma unroll
    for (int j = 0; j < 7; ++j) f1[j] = uload(h1 + j);

    // Phase 1: fp16 row filter -> LDS (38 rows x 8 groups of 8 cols)
    for (int e = tid; e < 38 * 8; e += 256) {
      int r = e >> 3, g = e & 7;
      int row = refl((h2_0 << 1) - 3 + r, H);
      const __half* xr = xp + (size_t)row * W;
      int cb = c0 + (g << 3);
      float v[16];
      if (cb >= 4 && cb + 12 <= W) {
        union { uint2 u; __half2 h[2]; } q0, q1, q2, q3;
        q0.u = *(const uint2*)(xr + cb - 4);
        q1.u = *(const uint2*)(xr + cb);
        q2.u = *(const uint2*)(xr + cb + 4);
        q3.u = *(const uint2*)(xr + cb + 8);
        float2 t;
        t = __half22float2(q0.h[0]); v[0] = t.x; v[1] = t.y;
        t = __half22float2(q0.h[1]); v[2] = t.x; v[3] = t.y;
        t = __half22float2(q1.h[0]); v[4] = t.x; v[5] = t.y;
        t = __half22float2(q1.h[1]); v[6] = t.x; v[7] = t.y;
        t = __half22float2(q2.h[0]); v[8] = t.x; v[9] = t.y;
        t = __half22float2(q2.h[1]); v[10] = t.x; v[11] = t.y;
        t = __half22float2(q3.h[0]); v[12] = t.x; v[13] = t.y;
        t = __half22float2(q3.h[1]); v[14] = t.x; v[15] = t.y;
      } else {
        v[0] = 0.f; v[15] = 0.f;
#pragma unroll
        for (int t2 = 1; t2 <= 14; ++t2) v[t2] = __half2float(xr[refl(cb - 4 + t2, W)]);
      }
      float o0[8], o1[8];
      filt8_win(v, f0, f1, o0, o1);
      *(float4*)&lo_s[r * J1_STRIDE + (g << 3)] = make_float4(o0[0], o0[1], o0[2], o0[3]);
      *(float4*)&lo_s[r * J1_STRIDE + (g << 3) + 4] = make_float4(o0[4], o0[5], o0[6], o0[7]);
      *(float4*)&hi_s[r * J1_STRIDE + (g << 3)] = make_float4(o1[0], o1[1], o1[2], o1[3]);
      *(float4*)&hi_s[r * J1_STRIDE + (g << 3) + 4] = make_float4(o1[4], o1[5], o1[6], o1[7]);
    }
    __syncthreads();

    int c18 = p % 18, n = p / 18;
    int o1i = c18 / 3, ch = c18 - 3 * o1i;
    float* ob = out + (size_t)n * 147 * spo;
    int hq = tid >> 4, wq = tid & 15;
    int h2 = h2_0 + hq;
    int w2 = w2_0 + (wq << 1);
    J1Acc A;
    j1_colfilt4(lo_s, hi_s, hq << 1, wq << 2, f0, f1, &A);
    size_t px = ((size_t)h2 << 7) + w2;
    float pl0 = 0.25f * (A.ll[0][0] + A.ll[0][1] + A.ll[1][0] + A.ll[1][1]);
    float pl1 = 0.25f * (A.ll[0][2] + A.ll[0][3] + A.ll[1][2] + A.ll[1][3]);
    nt_store_f2(&ob[(size_t)((1 + o1i) * 3 + ch) * spo + px], pl0, pl1);
    float m2[6][2];
#pragma unroll
    for (int k = 0; k < 2; ++k) {
      q2c_mag_k(A.lh, k, &m2[0][k], &m2[5][k]);
      q2c_mag_k(A.hh, k, &m2[1][k], &m2[4][k]);
      q2c_mag_k(A.hl, k, &m2[2][k], &m2[3][k]);
    }
#pragma unroll
    for (int o2 = 0; o2 < 6; ++o2) {
      nt_store_f2(&ob[(size_t)((13 + o2 * 6 + o1i) * 3 + ch) * spo + px],
                  m2[o2][0], m2[o2][1]);
    }
  }
}

extern "C" void kernel_launch(void* const* d_in, const int* in_sizes, int n_in,
                              void* d_out, int out_size, void* d_ws, size_t ws_size,
                              hipStream_t stream) {
  const float* x   = (const float*)d_in[0];
  const float* h0o = (const float*)d_in[1];
  const float* h1o = (const float*)d_in[2];
  const float* h0a = (const float*)d_in[3];
  const float* h0b = (const float*)d_in[4];
  const float* h1a = (const float*)d_in[5];
  const float* h1b = (const float*)d_in[6];
  float* out = (float*)d_out;
  char* ws = (char*)d_ws;
  (void)in_sizes; (void)n_in; (void)out_size; (void)ws_size;

  // Workspace: s0 f32 (24x512x512 = 24 MB), pb fp16 (8x18x256x256 = 18.9 MB)
  const size_t SZ_S0 = (size_t)24 * 512 * 512 * sizeof(float);
  float* s0 = (float*)ws;
  __half* pb = (__half*)(ws + SZ_S0);

  k_fused_j1a<<<3072, 256, 0, stream>>>(x, h0o, h1o, s0, pb);
  k_fused_bc<<<6144, 256, 0, stream>>>(s0, pb, h0a, h0b, h1a, h1b, h0o, h1o, out);
}